// Round 10
// baseline (47.807 us; speedup 1.0000x reference)
//
#include <hip/hip_runtime.h>
#include <cstddef>

#define SLEN 8192
#define CIN  32
#define COUT 8
#define BATCH 128
#define BK 4                      // batches per thread
#define LOG2E2 2.885390081777927f // 2*log2(e)

typedef float v2f __attribute__((ext_vector_type(2)));
typedef float v4f __attribute__((ext_vector_type(4)));

__device__ __forceinline__ float exp2_fast(float x) {
    float r; asm("v_exp_f32 %0, %1" : "=v"(r) : "v"(x)); return r;
}
// tanh(u) given v = u * 2*log2(e): 1 - 2/(exp2(v)+1); saturates via rcp(inf)=0.
__device__ __forceinline__ float tanh_scaled(float v) {
    float t = exp2_fast(v);
    return 1.0f - 2.0f * __builtin_amdgcn_rcpf(t + 1.0f);
}
__device__ __forceinline__ v2f tanh_scaled2(v2f v) {
    v2f r; r.x = tanh_scaled(v.x); r.y = tanh_scaled(v.y); return r;
}

// Kernel 1: wsum[j,s] = (sum_i w1[i,j,s]) * 2*log2(e)
__global__ __launch_bounds__(256) void lc3_wsum(const float* __restrict__ w1,
                                                float* __restrict__ wsum) {
    __shared__ v4f part[4][64];
    const int tx = threadIdx.x & 63;
    const int ty = threadIdx.x >> 6;
    const int g  = blockIdx.x * 64 + tx;       // float4-output index
    const int j  = g >> 11;
    const int s4 = g & 2047;

    v4f acc = (v4f)(0.f);
    #pragma unroll
    for (int ii = 0; ii < 8; ++ii) {
        const int i = ty * 8 + ii;
        acc += *reinterpret_cast<const v4f*>(
            &w1[(size_t)(i * CIN + j) * SLEN + (size_t)s4 * 4]);
    }
    part[ty][tx] = acc;
    __syncthreads();
    if (ty == 0) {
        v4f r = (part[0][tx] + part[1][tx] + part[2][tx] + part[3][tx]) * LOG2E2;
        *reinterpret_cast<v4f*>(&wsum[(size_t)j * SLEN + (size_t)s4 * 4]) = r;
    }
}

// Kernel 2: VW=2 (v2f loads) + BK=4 + JSPLIT=2.
// Wave-pair jh=0 handles j<16, jh=1 handles j>=16; LDS-combine at the end.
// Same occupancy (16 waves/CU), bytes, and w2 reuse as the R7 scalar kernel,
// but half the VMEM instructions and 2x bytes-in-flight per vmcnt slot.
__global__ __launch_bounds__(256, 4) void lc3_main(const float* __restrict__ x,
                                                   const float* __restrict__ w2,
                                                   const float* __restrict__ bias,
                                                   const float* __restrict__ wsum,
                                                   float* __restrict__ out) {
    __shared__ v2f part[BK][COUT][128];        // 32 KB
    const int tl = threadIdx.x & 127;
    const int jh = threadIdx.x >> 7;
    const int s  = (blockIdx.x * 128 + tl) * 2;
    const int b0 = blockIdx.y * BK;
    const int jb = jh * 16;

    const float* wp = wsum + (size_t)jb * SLEN + s;
    const float* xb[BK];
    #pragma unroll
    for (int k = 0; k < BK; ++k)
        xb[k] = x + ((size_t)(b0 + k) * CIN + jb) * SLEN + s;
    const float* w2b[COUT];
    #pragma unroll
    for (int o = 0; o < COUT; ++o)
        w2b[o] = w2 + ((size_t)o * CIN + jb) * SLEN + s;

    v2f acc[BK][COUT];
    #pragma unroll
    for (int k = 0; k < BK; ++k)
        #pragma unroll
        for (int o = 0; o < COUT; ++o) acc[k][o] = (v2f)(0.f);

    #pragma unroll 4
    for (int j = 0; j < 16; ++j) {
        const size_t off = (size_t)j * SLEN;
        const v2f wsv = *reinterpret_cast<const v2f*>(&wp[off]);
        v2f h[BK];
        #pragma unroll
        for (int k = 0; k < BK; ++k) {
            const v2f xv = *reinterpret_cast<const v2f*>(&xb[k][off]);
            h[k] = tanh_scaled2(xv * wsv);     // wsum pre-scaled by 2*log2e
        }
        #pragma unroll
        for (int o = 0; o < COUT; ++o) {
            const v2f wv = *reinterpret_cast<const v2f*>(&w2b[o][off]);
            #pragma unroll
            for (int k = 0; k < BK; ++k)
                acc[k][o] += h[k] * wv;        // v_pk_fma_f32
        }
    }

    if (jh) {
        #pragma unroll
        for (int k = 0; k < BK; ++k)
            #pragma unroll
            for (int o = 0; o < COUT; ++o)
                part[k][o][tl] = acc[k][o];
    }
    __syncthreads();
    if (!jh) {
        #pragma unroll
        for (int o = 0; o < COUT; ++o) {
            const v2f bv = *reinterpret_cast<const v2f*>(&bias[o * SLEN + s]);
            #pragma unroll
            for (int k = 0; k < BK; ++k) {
                const v2f t = (acc[k][o] + part[k][o][tl] + bv) * LOG2E2;
                const v2f r = tanh_scaled2(t);
                *reinterpret_cast<v2f*>(&out[((size_t)(b0 + k) * COUT + o) * SLEN + s]) = r;
            }
        }
    }
}

extern "C" void kernel_launch(void* const* d_in, const int* in_sizes, int n_in,
                              void* d_out, int out_size, void* d_ws, size_t ws_size,
                              hipStream_t stream) {
    const float* x    = (const float*)d_in[0];
    const float* w1   = (const float*)d_in[1];
    const float* w2   = (const float*)d_in[2];
    const float* bias = (const float*)d_in[3];
    float* out  = (float*)d_out;
    float* wsum = (float*)d_ws;   // 1 MB scratch

    // wsum: 65536 float4 outputs, 64/block -> 1024 blocks
    lc3_wsum<<<dim3(CIN * SLEN / 4 / 64), dim3(256), 0, stream>>>(w1, wsum);

    // main: (32 s-tiles, 32 b-tiles) = 1024 blocks x 256 thr = 16 waves/CU;
    // linear dispatch: XCD = bx%8 -> each s-tile's w2 slice stays XCD-local
    dim3 grid(SLEN / 256, BATCH / BK);
    lc3_main<<<grid, dim3(256), 0, stream>>>(x, w2, bias, wsum, out);
}

// Round 11
// 40.977 us; speedup vs baseline: 1.1667x; 1.1667x over previous
//
#include <hip/hip_runtime.h>
#include <cstddef>

#define SLEN 8192
#define CIN  32
#define COUT 8
#define BATCH 128
#define BK 4                      // batches per thread
#define LOG2E2 2.885390081777927f // 2*log2(e)

typedef float v4f __attribute__((ext_vector_type(4)));

__device__ __forceinline__ float exp2_fast(float x) {
    float r; asm("v_exp_f32 %0, %1" : "=v"(r) : "v"(x)); return r;
}
// tanh(u) given v = u * 2*log2(e): 1 - 2/(exp2(v)+1); saturates via rcp(inf)=0.
__device__ __forceinline__ float tanh_scaled(float v) {
    float t = exp2_fast(v);
    return 1.0f - 2.0f * __builtin_amdgcn_rcpf(t + 1.0f);
}

// Kernel 1: wsum[j,s] = (sum_i w1[i,j,s]) * 2*log2(e)
__global__ __launch_bounds__(256) void lc3_wsum(const float* __restrict__ w1,
                                                float* __restrict__ wsum) {
    __shared__ v4f part[4][64];
    const int tx = threadIdx.x & 63;
    const int ty = threadIdx.x >> 6;
    const int g  = blockIdx.x * 64 + tx;       // float4-output index
    const int j  = g >> 11;
    const int s4 = g & 2047;

    v4f acc = (v4f)(0.f);
    #pragma unroll
    for (int ii = 0; ii < 8; ++ii) {
        const int i = ty * 8 + ii;
        acc += *reinterpret_cast<const v4f*>(
            &w1[(size_t)(i * CIN + j) * SLEN + (size_t)s4 * 4]);
    }
    part[ty][tx] = acc;
    __syncthreads();
    if (ty == 0) {
        v4f r = (part[0][tx] + part[1][tx] + part[2][tx] + part[3][tx]) * LOG2E2;
        *reinterpret_cast<v4f*>(&wsum[(size_t)j * SLEN + (size_t)s4 * 4]) = r;
    }
}

// Kernel 2: best-known base (R7: scalar coalesced, BK=4, 1024x256 = 16 waves/CU)
// + nontemporal OUT stores only. out is write-only during timed replays, so
// keeping it out of L3 frees ~32 MB of capacity for the x re-read stream.
// (R3 proved NT on x-LOADS is harmful; this isolates the store side.)
__global__ __launch_bounds__(256, 4) void lc3_main(const float* __restrict__ x,
                                                   const float* __restrict__ w2,
                                                   const float* __restrict__ bias,
                                                   const float* __restrict__ wsum,
                                                   float* __restrict__ out) {
    const int s  = blockIdx.x * 256 + threadIdx.x;
    const int b0 = blockIdx.y * BK;

    const float* wp = wsum + s;
    const float* xb[BK];
    #pragma unroll
    for (int k = 0; k < BK; ++k) xb[k] = x + ((size_t)(b0 + k) * CIN) * SLEN + s;
    const float* w2b[COUT];
    #pragma unroll
    for (int o = 0; o < COUT; ++o) w2b[o] = w2 + ((size_t)o * CIN) * SLEN + s;

    float acc[BK][COUT];
    #pragma unroll
    for (int k = 0; k < BK; ++k)
        #pragma unroll
        for (int o = 0; o < COUT; ++o) acc[k][o] = 0.f;

    #pragma unroll 2
    for (int j = 0; j < CIN; ++j) {
        const size_t off = (size_t)j * SLEN;
        const float wsv = wp[off];
        float h[BK];
        #pragma unroll
        for (int k = 0; k < BK; ++k) h[k] = tanh_scaled(xb[k][off] * wsv);
        #pragma unroll
        for (int o = 0; o < COUT; ++o) {
            const float wv = w2b[o][off];
            #pragma unroll
            for (int k = 0; k < BK; ++k)
                acc[k][o] = fmaf(h[k], wv, acc[k][o]);
        }
    }

    #pragma unroll
    for (int o = 0; o < COUT; ++o) {
        const float bsc = bias[o * SLEN + s] * LOG2E2;
        #pragma unroll
        for (int k = 0; k < BK; ++k) {
            const float r = tanh_scaled(fmaf(acc[k][o], LOG2E2, bsc));
            __builtin_nontemporal_store(
                r, &out[((size_t)(b0 + k) * COUT + o) * SLEN + s]);
        }
    }
}

extern "C" void kernel_launch(void* const* d_in, const int* in_sizes, int n_in,
                              void* d_out, int out_size, void* d_ws, size_t ws_size,
                              hipStream_t stream) {
    const float* x    = (const float*)d_in[0];
    const float* w1   = (const float*)d_in[1];
    const float* w2   = (const float*)d_in[2];
    const float* bias = (const float*)d_in[3];
    float* out  = (float*)d_out;
    float* wsum = (float*)d_ws;   // 1 MB scratch

    // wsum: 65536 float4 outputs, 64/block -> 1024 blocks
    lc3_wsum<<<dim3(CIN * SLEN / 4 / 64), dim3(256), 0, stream>>>(w1, wsum);

    // main: (32 s-tiles, 32 b-tiles) = 1024 blocks x 256 thr = 16 waves/CU;
    // linear dispatch: XCD = bx%8 -> all 32 b-tiles of an s-tile share an XCD,
    // keeping that s-tile's w2/wsum slice L2-local
    dim3 grid(SLEN / 256, BATCH / BK);
    lc3_main<<<grid, dim3(256), 0, stream>>>(x, w2, bias, wsum, out);
}